// Round 6
// baseline (178.957 us; speedup 1.0000x reference)
//
#include <hip/hip_runtime.h>
#include <hip/hip_bf16.h>

// SpikingPolicyNet: B=8192, D_in=256, H=1024, D_out=64, T=15, TAU=20, V_TH=1
//
// Pipeline:
//  K0 : W2 -> W2cb (bf16 W2^T, signed) + W2p (relu'd bf16 W2^T)  [2+2 MB]
//  K0b: Wout -> WoutT (f32, 1024x64) for coalesced rare-path readout
//  K1 : bf16-MFMA x@W1.T; epilogue folds b1 and emits the closed-form spike
//       interval k = ceil(log2(1-1/I)/log2(0.95)) as a BYTE PLANE kb[b][j]
//       (spikes at t = k,2k,...; I1 time-invariant).
//  K2 : ONE WAVE PER ROW, zero barriers. 16 neurons/lane. Ballot-built
//       spiker list (no atomics); one coalesced gather pass accumulates the
//       spike-free bound U = b2 + sum_spikers relu(W2 col) >= max_t I2_t.
//       Induction v2_t <= U*(1-.95^t) < U, so U <= 0.999 (margin >> fp
//       drift) proves zero s2 spikes -> skip everything (out = bout,
//       bit-exact; validated absmax==0 in R1-R5). Rare waves run the exact
//       per-step sim wave-locally.

#define B_SZ   8192
#define D_IN   256
#define H_SZ   1024
#define D_OUT  64
#define T_STEPS 15
#define SKIP_THR 0.999f

typedef __attribute__((ext_vector_type(8))) short short8;
typedef __attribute__((ext_vector_type(4))) float f32x4;

static __device__ __forceinline__ unsigned int pk_bf16(float lo, float hi) {
    return (__builtin_bit_cast(unsigned int, hi) & 0xffff0000u) |
           (__builtin_bit_cast(unsigned int, lo) >> 16);
}

// packed bf16 pair -> two f32 adds into arr[u0], arr[u0+1] (exact unpack)
#define ADDPK(arr, w, u0)                                                     \
    { arr[(u0)]     += __builtin_bit_cast(float, (w) << 16);                  \
      arr[(u0) + 1] += __builtin_bit_cast(float, (w) & 0xffff0000u); }
#define ADD8(arr, q, u0)                                                      \
    { ADDPK(arr, (q).x, (u0))     ADDPK(arr, (q).y, (u0) + 2)                 \
      ADDPK(arr, (q).z, (u0) + 4) ADDPK(arr, (q).w, (u0) + 6) }

// ---------------------------------------------------------------- K0: W2 -> W2cb + W2p
__global__ __launch_bounds__(256) void k0_transpose(const float* __restrict__ W2,
                                                    unsigned short* __restrict__ W2cb,
                                                    unsigned short* __restrict__ W2p) {
    __shared__ float tile[32][33];
    const int bx = blockIdx.x * 32;
    const int by = blockIdx.y * 32;
    const int tx = threadIdx.x;
    const int ty = threadIdx.y;
    #pragma unroll
    for (int i = ty; i < 32; i += 8)
        tile[i][tx] = W2[(by + i) * H_SZ + bx + tx];
    __syncthreads();
    #pragma unroll
    for (int i = ty; i < 32; i += 8) {
        const unsigned int uv = __builtin_bit_cast(unsigned int, tile[tx][i]);
        const unsigned short bf = (unsigned short)(uv >> 16);
        const size_t idx = (size_t)(bx + i) * H_SZ + by + tx;
        W2cb[idx] = bf;
        W2p[idx]  = (bf & 0x8000u) ? (unsigned short)0 : bf;   // relu (exact on bf16)
    }
}

// ---------------------------------------------------------------- K0b: Wout -> WoutT (1024x64)
__global__ __launch_bounds__(256) void k0b_woutT(const float* __restrict__ Wout,
                                                 float* __restrict__ WoutT) {
    __shared__ float tile[32][33];
    const int bx = blockIdx.x * 32;   // source col (j)
    const int by = blockIdx.y * 32;   // source row (o)
    const int tx = threadIdx.x;
    const int ty = threadIdx.y;
    #pragma unroll
    for (int i = ty; i < 32; i += 8)
        tile[i][tx] = Wout[(by + i) * H_SZ + bx + tx];
    __syncthreads();
    #pragma unroll
    for (int i = ty; i < 32; i += 8)
        WoutT[(bx + i) * D_OUT + by + tx] = tile[tx][i];
}

// ---------------------------------------------------------------- K1: interval byte-plane from x@W1.T+b1
__global__ __launch_bounds__(256) void k1_mfma(const float* __restrict__ A,
                                               const float* __restrict__ Bw,
                                               const float* __restrict__ b1,
                                               unsigned char* __restrict__ kb) {
    __shared__ unsigned int As4[2048];   // 128 rows x 32 bf16, 16B-chunk XOR swizzle
    __shared__ unsigned int Bs4[2048];
    const int tid  = threadIdx.x;
    const int m0   = blockIdx.x * 128;
    const int n0   = blockIdx.y * 128;
    const int lane = tid & 63;
    const int wid  = tid >> 6;
    const int wr   = wid >> 1, wc = wid & 1;

    const int row0 = tid >> 2;
    const int row1 = row0 + 64;
    const int q0   = tid & 3;

    f32x4 acc[4][4] = {};
    float4 s0[8], s1[8];

    auto LOAD = [&](float4* s, int kbk) {
        const float* pa0 = A  + (m0 + row0) * D_IN + kbk + q0 * 8;
        const float* pa1 = A  + (m0 + row1) * D_IN + kbk + q0 * 8;
        const float* pb0 = Bw + (n0 + row0) * D_IN + kbk + q0 * 8;
        const float* pb1 = Bw + (n0 + row1) * D_IN + kbk + q0 * 8;
        s[0] = *(const float4*)pa0; s[1] = *(const float4*)(pa0 + 4);
        s[2] = *(const float4*)pa1; s[3] = *(const float4*)(pa1 + 4);
        s[4] = *(const float4*)pb0; s[5] = *(const float4*)(pb0 + 4);
        s[6] = *(const float4*)pb1; s[7] = *(const float4*)(pb1 + 4);
    };
    auto WRITE = [&](const float4* s) {
        const int i0 = row0 * 16 + (q0 ^ ((row0 >> 1) & 3)) * 4;
        const int i1 = row1 * 16 + (q0 ^ ((row1 >> 1) & 3)) * 4;
        *(uint4*)&As4[i0] = make_uint4(pk_bf16(s[0].x, s[0].y), pk_bf16(s[0].z, s[0].w),
                                       pk_bf16(s[1].x, s[1].y), pk_bf16(s[1].z, s[1].w));
        *(uint4*)&As4[i1] = make_uint4(pk_bf16(s[2].x, s[2].y), pk_bf16(s[2].z, s[2].w),
                                       pk_bf16(s[3].x, s[3].y), pk_bf16(s[3].z, s[3].w));
        *(uint4*)&Bs4[i0] = make_uint4(pk_bf16(s[4].x, s[4].y), pk_bf16(s[4].z, s[4].w),
                                       pk_bf16(s[5].x, s[5].y), pk_bf16(s[5].z, s[5].w));
        *(uint4*)&Bs4[i1] = make_uint4(pk_bf16(s[6].x, s[6].y), pk_bf16(s[6].z, s[6].w),
                                       pk_bf16(s[7].x, s[7].y), pk_bf16(s[7].z, s[7].w));
    };
    auto COMPUTE = [&]() {
        short8 afr[4], bfr[4];
        const int q  = lane >> 4;
        const int lr = lane & 15;
        #pragma unroll
        for (int mf = 0; mf < 4; ++mf) {
            const int ra = wr * 64 + mf * 16 + lr;
            afr[mf] = *(const short8*)&As4[ra * 16 + (q ^ ((ra >> 1) & 3)) * 4];
            const int rb = wc * 64 + mf * 16 + lr;
            bfr[mf] = *(const short8*)&Bs4[rb * 16 + (q ^ ((rb >> 1) & 3)) * 4];
        }
        #pragma unroll
        for (int mf = 0; mf < 4; ++mf)
            #pragma unroll
            for (int nf = 0; nf < 4; ++nf)
                acc[mf][nf] = __builtin_amdgcn_mfma_f32_16x16x32_bf16(
                    afr[mf], bfr[nf], acc[mf][nf], 0, 0, 0);
    };

    LOAD(s0, 0);
    for (int kk = 0; kk < D_IN; kk += 64) {
        if (kk + 32 < D_IN) LOAD(s1, kk + 32);
        __syncthreads();
        WRITE(s0);
        __syncthreads();
        COMPUTE();
        if (kk + 64 < D_IN) LOAD(s0, kk + 64);
        __syncthreads();
        WRITE(s1);
        __syncthreads();
        COMPUTE();
    }

    // Epilogue: I = acc + b1[col]; k = ceil(log2(1-1/I)*-13.5134035), 0 = none.
    // C/D layout (m89): col = lane&15, row = (lane>>4)*4 + r. Byte-plane store.
    const int lr = lane & 15;
    const int qq = lane >> 4;
    float b1v[4];
    #pragma unroll
    for (int nf = 0; nf < 4; ++nf) b1v[nf] = b1[n0 + wc * 64 + nf * 16 + lr];

    #pragma unroll
    for (int mf = 0; mf < 4; ++mf) {
        const int rbase = m0 + wr * 64 + mf * 16 + qq * 4;
        #pragma unroll
        for (int nf = 0; nf < 4; ++nf) {
            const int c = n0 + wc * 64 + nf * 16 + lr;
            #pragma unroll
            for (int r = 0; r < 4; ++r) {
                const float I = acc[mf][nf][r] + b1v[nf];
                int k = 0;
                if (I > 1.8632055f) {
                    const float l2 = __builtin_amdgcn_logf(1.0f - __builtin_amdgcn_rcpf(I));
                    int kc = (int)__builtin_ceilf(l2 * -13.5134035f);
                    k = kc < 1 ? 1 : (kc > 15 ? 15 : kc);
                }
                kb[(size_t)(rbase + r) * H_SZ + c] = (unsigned char)k;
            }
        }
    }
}

// ---------------------------------------------------------------- K2: wave-per-row, barrier-free
__global__ __launch_bounds__(256, 4) void k2_snn(const unsigned char* __restrict__ kb,
                                                 const unsigned short* __restrict__ W2cb,
                                                 const unsigned short* __restrict__ W2p,
                                                 const float* __restrict__ b2,
                                                 const float* __restrict__ WoutT,
                                                 const float* __restrict__ bout,
                                                 float* __restrict__ out) {
    const int wid  = threadIdx.x >> 6;
    const int lane = threadIdx.x & 63;
    const int b    = blockIdx.x * 4 + wid;          // this wave's row

    __shared__ unsigned int list_s[4][H_SZ];        // per-wave private segment
    unsigned int* list = list_s[wid];

    // ---- 16 interval bytes for this lane's neurons (coalesced 16B/lane)
    const uint4 kw = *(const uint4*)(kb + (size_t)b * H_SZ + lane * 16);
    const unsigned int kws[4] = {kw.x, kw.y, kw.z, kw.w};

    // ---- U starts at b2 (becomes the spike-free bound)
    float U[16];
    {
        const float4 q0 = *(const float4*)&b2[lane * 16 + 0];
        const float4 q1 = *(const float4*)&b2[lane * 16 + 4];
        const float4 q2 = *(const float4*)&b2[lane * 16 + 8];
        const float4 q3 = *(const float4*)&b2[lane * 16 + 12];
        U[0]=q0.x; U[1]=q0.y; U[2]=q0.z;  U[3]=q0.w;
        U[4]=q1.x; U[5]=q1.y; U[6]=q1.z;  U[7]=q1.w;
        U[8]=q2.x; U[9]=q2.y; U[10]=q2.z; U[11]=q2.w;
        U[12]=q3.x;U[13]=q3.y;U[14]=q3.z; U[15]=q3.w;
    }

    // ---- ballot-built spiker list (no atomics, no barriers)
    int base = 0;
    #pragma unroll
    for (int u = 0; u < 16; ++u) {
        const int k = (int)((kws[u >> 2] >> ((u & 3) * 8)) & 0xffu);
        const unsigned long long m = __ballot(k != 0);
        if (k) {
            const int pos = base + (int)__popcll(m & ((1ull << lane) - 1ull));
            list[pos] = ((unsigned int)(lane * 16 + u) << 8) | (unsigned int)k;
        }
        base += (int)__popcll(m);
    }
    const int n = base;
    __builtin_amdgcn_sched_barrier(0);

    // ---- gather pass: U += relu(W2 col j) for each spiker j (coalesced 2KB/spiker)
    int i = 0;
    for (; i + 1 < n; i += 2) {
        const int ja = __builtin_amdgcn_readfirstlane((int)(list[i] >> 8));
        const int jb = __builtin_amdgcn_readfirstlane((int)(list[i + 1] >> 8));
        const uint4 wa0 = *(const uint4*)(W2p + ((size_t)ja << 10) + lane * 16);
        const uint4 wa1 = *(const uint4*)(W2p + ((size_t)ja << 10) + lane * 16 + 8);
        const uint4 wb0 = *(const uint4*)(W2p + ((size_t)jb << 10) + lane * 16);
        const uint4 wb1 = *(const uint4*)(W2p + ((size_t)jb << 10) + lane * 16 + 8);
        ADD8(U, wa0, 0) ADD8(U, wa1, 8)
        ADD8(U, wb0, 0) ADD8(U, wb1, 8)
    }
    if (i < n) {
        const int ja = __builtin_amdgcn_readfirstlane((int)(list[i] >> 8));
        const uint4 wa0 = *(const uint4*)(W2p + ((size_t)ja << 10) + lane * 16);
        const uint4 wa1 = *(const uint4*)(W2p + ((size_t)ja << 10) + lane * 16 + 8);
        ADD8(U, wa0, 0) ADD8(U, wa1, 8)
    }

    bool need = false;
    #pragma unroll
    for (int u = 0; u < 16; ++u) need |= (U[u] > SKIP_THR);

    if (__ballot(need) == 0) {          // proven spike-free: out = bout (bit-exact)
        out[(size_t)b * D_OUT + lane] = bout[lane];
        return;
    }

    // ---- rare exact path (wave-local): per-step re-gather simulation
    float v2[16];
    #pragma unroll
    for (int u = 0; u < 16; ++u) v2[u] = 0.f;
    unsigned int clo = 0, chi = 0;      // nibble-packed spike counts

    for (int t = 1; t <= T_STEPS; ++t) {
        float i2[16];
        {
            const float4 q0 = *(const float4*)&b2[lane * 16 + 0];
            const float4 q1 = *(const float4*)&b2[lane * 16 + 4];
            const float4 q2 = *(const float4*)&b2[lane * 16 + 8];
            const float4 q3 = *(const float4*)&b2[lane * 16 + 12];
            i2[0]=q0.x; i2[1]=q0.y; i2[2]=q0.z;  i2[3]=q0.w;
            i2[4]=q1.x; i2[5]=q1.y; i2[6]=q1.z;  i2[7]=q1.w;
            i2[8]=q2.x; i2[9]=q2.y; i2[10]=q2.z; i2[11]=q2.w;
            i2[12]=q3.x;i2[13]=q3.y;i2[14]=q3.z; i2[15]=q3.w;
        }
        for (int s = 0; s < n; ++s) {
            const unsigned int e = list[s];
            const int k = (int)(e & 0xffu);
            if ((t % k) == 0) {
                const int j = __builtin_amdgcn_readfirstlane((int)(e >> 8));
                const uint4 w0 = *(const uint4*)(W2cb + ((size_t)j << 10) + lane * 16);
                const uint4 w1 = *(const uint4*)(W2cb + ((size_t)j << 10) + lane * 16 + 8);
                ADD8(i2, w0, 0) ADD8(i2, w1, 8)
            }
        }
        #pragma unroll
        for (int u = 0; u < 16; ++u) {
            v2[u] = fmaf(i2[u], 0.05f, v2[u] * 0.95f);
            if (v2[u] > 1.0f) {
                v2[u] = 0.f;
                if (u < 8) clo += 1u << (4 * u); else chi += 1u << (4 * (u - 8));
            }
        }
    }

    if (__ballot((clo | chi) != 0) == 0) {   // simulated, but no s2 spikes
        out[(size_t)b * D_OUT + lane] = bout[lane];
        return;
    }

    // ---- full readout for this row: rr in the wave's LDS segment (list dead)
    float* rr = (float*)list;
    #pragma unroll
    for (int u = 0; u < 16; ++u) {
        const unsigned int cu = (u < 8) ? ((clo >> (4 * u)) & 15u)
                                        : ((chi >> (4 * (u - 8))) & 15u);
        rr[lane * 16 + u] = (float)cu / 15.0f;
    }
    __builtin_amdgcn_sched_barrier(0);
    float acc = bout[lane];
    for (int j = 0; j < H_SZ; j += 4) {
        acc = fmaf(rr[j + 0], WoutT[(j + 0) * D_OUT + lane], acc);
        acc = fmaf(rr[j + 1], WoutT[(j + 1) * D_OUT + lane], acc);
        acc = fmaf(rr[j + 2], WoutT[(j + 2) * D_OUT + lane], acc);
        acc = fmaf(rr[j + 3], WoutT[(j + 3) * D_OUT + lane], acc);
    }
    out[(size_t)b * D_OUT + lane] = acc;
}

// ---------------------------------------------------------------- launch
extern "C" void kernel_launch(void* const* d_in, const int* in_sizes, int n_in,
                              void* d_out, int out_size, void* d_ws, size_t ws_size,
                              hipStream_t stream) {
    const float* x    = (const float*)d_in[0];
    const float* W1   = (const float*)d_in[1];
    const float* b1   = (const float*)d_in[2];
    const float* W2   = (const float*)d_in[3];
    const float* b2   = (const float*)d_in[4];
    const float* Wout = (const float*)d_in[5];
    const float* bout = (const float*)d_in[6];
    float* out = (float*)d_out;

    char* ws = (char*)d_ws;
    unsigned short* W2cb  = (unsigned short*)(ws);                 // 2 MB
    unsigned short* W2p   = (unsigned short*)(ws + (2 << 20));     // 2 MB
    float*          WoutT = (float*)(ws + (4 << 20));              // 256 KB
    unsigned char*  kbuf  = (unsigned char*)(ws + (8 << 20));      // 8 MB

    k0_transpose<<<dim3(H_SZ / 32, H_SZ / 32), dim3(32, 8), 0, stream>>>(W2, W2cb, W2p);
    k0b_woutT<<<dim3(H_SZ / 32, D_OUT / 32), dim3(32, 8), 0, stream>>>(Wout, WoutT);
    k1_mfma<<<dim3(B_SZ / 128, H_SZ / 128), 256, 0, stream>>>(x, W1, b1, kbuf);
    k2_snn<<<B_SZ / 4, 256, 0, stream>>>(kbuf, W2cb, W2p, b2, WoutT, bout, out);
}